// Round 1
// baseline (381.375 us; speedup 1.0000x reference)
//
#include <hip/hip_runtime.h>
#include <cmath>

namespace {

constexpr int R_ = 8, M1_ = 32, N1_ = 64, M2_ = 24, N2_ = 48;
constexpr int DIN = 768;          // M1*M2
constexpr int T_TOK = 8;          // tokens per workgroup
constexpr int NTHREADS = 512;     // 8 waves

// ---- LDS layout (float offsets). Phase1: XP + T1. Phase2: HG + S2T (overlaps
// phase1 after a barrier). OUT partials reuse dead HG region at the end.
constexpr int XP_F     = 0;
constexpr int XP_PLANE = 197;                    // 24*8 + 5 (bank spread, i-plane)
constexpr int T1_F     = XP_F + M1_ * XP_PLANE;  // 6304
constexpr int T1_JS    = 10;                     // j-stride (breaks 8-float aliasing)
constexpr int T1_PLANE = 482;                    // 48*10 + 2
constexpr int HG_F     = 0;
constexpr int HG_PLANE = 388;                    // 48*8 + 4
constexpr int S2_F     = HG_F + N1_ * HG_PLANE;  // 24832
constexpr int S2_PLANE = 196;                    // 8*24 + 4
constexpr int OUT0_F   = 0;                      // stride 9 per (m1,m2) row
constexpr int OUT1_F   = DIN * 9;                // 6912
constexpr int LDS_FLOATS = S2_F + N1_ * S2_PLANE; // 37376 floats = 149504 B

__global__ __launch_bounds__(NTHREADS, 2)
void kn_fused(const float* __restrict__ x,
              const float* __restrict__ A1,
              const float* __restrict__ B1,
              const float* __restrict__ A2,
              const float* __restrict__ B2,
              const float* __restrict__ b1,
              const float* __restrict__ b2,
              const int* __restrict__ p_inv,
              const int* __restrict__ q,
              float* __restrict__ out)
{
    extern __shared__ float lds[];
    const int tid  = threadIdx.x;
    const int lane = tid & 63;
    // wave id, forced wave-uniform so weight indices become SGPR (s_load path)
    const int w = __builtin_amdgcn_readfirstlane(tid >> 6);   // 0..7

    const long tokBase = (long)blockIdx.x * T_TOK;

    // p_inv/q may be int64 (x64 jax) or int32. In a permutation two entries
    // can't both be 0, but int64 high words are always 0 -> deterministic test.
    const bool idx64 = (p_inv[1] == 0 && p_inv[3] == 0);

    // ---------------- fill XP: XP[i][k][t] = x[tok t][p_inv[i*24+k]] ----------
    {
        const float* xrow = x + (size_t)(tokBase + w) * DIN;   // wave w -> token w
        #pragma unroll
        for (int c = 0; c < DIN / 64; ++c) {
            const int kIdx = c * 64 + lane;
            const int pidx = idx64 ? p_inv[2 * kIdx] : p_inv[kIdx];
            const float v  = xrow[pidx];
            lds[XP_F + (kIdx / M2_) * XP_PLANE + (kIdx % M2_) * 8 + w] = v;
        }
    }

    // h accumulators: wave owns n1-octet [8w,8w+8); lane: jg=lane>>2 (3 n2 cols),
    // tp=lane&3 (2 tokens) -> 8*3*2 = 48 regs, live across all r.
    float hacc[8][3][2];
    #pragma unroll
    for (int a = 0; a < 8; ++a)
        #pragma unroll
        for (int b = 0; b < 3; ++b) { hacc[a][b][0] = 0.f; hacc[a][b][1] = 0.f; }

    const int jg = lane >> 2;   // 0..15 -> j0 = 3*jg
    const int tp = lane & 3;    // 0..3  -> t = 2tp, 2tp+1
    const int ig = lane >> 3;   // 0..7  -> i0 = 4*ig   (stage s1)
    const int tl = lane & 7;    // 0..7  (stage s1 token)

    __syncthreads();

    // ---------------- block 1: for r: T1 = XP * B1_r ; hacc += A1_r * T1 ------
    for (int r = 0; r < R_; ++r) {
        // s1: T1[i][j][t] = sum_k XP[i][k][t] * B1[r][k][j], wave owns j in [6w,6w+6)
        float acc[4][6];
        #pragma unroll
        for (int a = 0; a < 4; ++a)
            #pragma unroll
            for (int b = 0; b < 6; ++b) acc[a][b] = 0.f;

        const float* B1r = B1 + ((size_t)r * M2_) * N2_ + 6 * w;  // uniform -> s_load
        #pragma unroll 6
        for (int k = 0; k < M2_; ++k) {
            float xv[4];
            #pragma unroll
            for (int di = 0; di < 4; ++di)
                xv[di] = lds[XP_F + (4 * ig + di) * XP_PLANE + k * 8 + tl];
            #pragma unroll
            for (int jj = 0; jj < 6; ++jj) {
                const float bw = B1r[k * N2_ + jj];
                #pragma unroll
                for (int di = 0; di < 4; ++di)
                    acc[di][jj] = fmaf(xv[di], bw, acc[di][jj]);
            }
        }
        __syncthreads();   // previous s2 finished reading T1
        #pragma unroll
        for (int di = 0; di < 4; ++di)
            #pragma unroll
            for (int jj = 0; jj < 6; ++jj)
                lds[T1_F + (4 * ig + di) * T1_PLANE + (6 * w + jj) * T1_JS + tl] = acc[di][jj];
        __syncthreads();

        // s2: hacc[nn][jj][tt] += A1[r][8w+nn][i] * T1[i][3jg+jj][2tp+tt]
        const float* A1r = A1 + ((size_t)r * N1_ + 8 * w) * M1_;  // uniform -> s_load
        #pragma unroll 4
        for (int i = 0; i < M1_; ++i) {
            float aw[8];
            #pragma unroll
            for (int nn = 0; nn < 8; ++nn) aw[nn] = A1r[nn * M1_ + i];
            float tv[3][2];
            #pragma unroll
            for (int jj = 0; jj < 3; ++jj)
                #pragma unroll
                for (int tt = 0; tt < 2; ++tt)
                    tv[jj][tt] = lds[T1_F + i * T1_PLANE + (3 * jg + jj) * T1_JS + 2 * tp + tt];
            #pragma unroll
            for (int nn = 0; nn < 8; ++nn)
                #pragma unroll
                for (int jj = 0; jj < 3; ++jj)
                    #pragma unroll
                    for (int tt = 0; tt < 2; ++tt)
                        hacc[nn][jj][tt] = fmaf(aw[nn], tv[jj][tt], hacc[nn][jj][tt]);
        }
    }

    __syncthreads();   // T1/XP dead; HG region (overlapping) is safe to write

    // ---------------- bias + exact GELU, write HG ----------------------------
    #pragma unroll
    for (int nn = 0; nn < 8; ++nn) {
        const int n = 8 * w + nn;
        #pragma unroll
        for (int jj = 0; jj < 3; ++jj) {
            const int j = 3 * jg + jj;
            const float bias = b1[n * N2_ + j];
            #pragma unroll
            for (int tt = 0; tt < 2; ++tt) {
                const float hv = hacc[nn][jj][tt] + bias;
                const float g  = 0.5f * hv * (1.0f + erff(hv * 0.70710678118654752f));
                lds[HG_F + n * HG_PLANE + j * 8 + 2 * tp + tt] = g;
            }
        }
    }
    __syncthreads();

    // ---------------- block 2 -------------------------------------------------
    // sA: wave owns n1-octet; lane: n1l=lane>>3, ta=lane&7 (token). 24 m2 accs.
    // sB: wave (kh=w>>2 k-half, mo=w&3 m1-octet); lane: m2g=lane&7, tb=lane>>3.
    float oacc[8][3];
    #pragma unroll
    for (int a = 0; a < 8; ++a)
        #pragma unroll
        for (int b = 0; b < 3; ++b) oacc[a][b] = 0.f;

    const int kh  = w >> 2;
    const int mo  = w & 3;
    const int n1l = lane >> 3;
    const int ta  = lane & 7;
    const int m2g = lane & 7;
    const int tb  = lane >> 3;

    for (int r = 0; r < R_; ++r) {
        // sA: sacc[m] = sum_k HG[8w+n1l][k][ta] * B2[r][k][m]
        float sacc[24];
        #pragma unroll
        for (int m = 0; m < 24; ++m) sacc[m] = 0.f;
        const float* B2r = B2 + (size_t)r * N2_ * M2_;            // uniform -> s_load
        const int n1 = 8 * w + n1l;
        #pragma unroll 4
        for (int k = 0; k < N2_; ++k) {
            const float hv = lds[HG_F + n1 * HG_PLANE + k * 8 + ta];
            #pragma unroll
            for (int m = 0; m < M2_; ++m)
                sacc[m] = fmaf(hv, B2r[k * M2_ + m], sacc[m]);
        }
        __syncthreads();   // previous sB finished reading S2T
        #pragma unroll
        for (int m = 0; m < M2_; ++m)
            lds[S2_F + n1 * S2_PLANE + ta * M2_ + m] = sacc[m];
        __syncthreads();

        // sB: oacc[mm][jj] += A2[r][8mo+mm][32kh+k] * S2T[32kh+k][tb][3m2g+jj]
        const float* A2r = A2 + ((size_t)r * M1_ + 8 * mo) * N1_ + 32 * kh; // uniform
        #pragma unroll 4
        for (int k = 0; k < 32; ++k) {
            float aw[8];
            #pragma unroll
            for (int mm = 0; mm < 8; ++mm) aw[mm] = A2r[mm * N1_ + k];
            float sv[3];
            #pragma unroll
            for (int jj = 0; jj < 3; ++jj)
                sv[jj] = lds[S2_F + (32 * kh + k) * S2_PLANE + tb * M2_ + 3 * m2g + jj];
            #pragma unroll
            for (int mm = 0; mm < 8; ++mm)
                #pragma unroll
                for (int jj = 0; jj < 3; ++jj)
                    oacc[mm][jj] = fmaf(aw[mm], sv[jj], oacc[mm][jj]);
        }
    }

    __syncthreads();   // HG dead; write k-half partial outputs into OUT regions
    #pragma unroll
    for (int mm = 0; mm < 8; ++mm)
        #pragma unroll
        for (int jj = 0; jj < 3; ++jj) {
            const int m1m2 = (8 * mo + mm) * M2_ + 3 * m2g + jj;
            lds[(kh ? OUT1_F : OUT0_F) + m1m2 * 9 + tb] = oacc[mm][jj];
        }
    __syncthreads();

    // ---------------- final: add halves + b2, apply q, coalesced store --------
    {
        float* orow = out + (size_t)(tokBase + w) * DIN;   // wave w -> token w
        #pragma unroll
        for (int c = 0; c < DIN / 64; ++c) {
            const int j  = c * 64 + lane;
            const int qj = idx64 ? q[2 * j] : q[j];
            const float v = lds[OUT0_F + qj * 9 + w] + lds[OUT1_F + qj * 9 + w] + b2[qj];
            orow[j] = v;
        }
    }
}

} // namespace

extern "C" void kernel_launch(void* const* d_in, const int* in_sizes, int n_in,
                              void* d_out, int out_size, void* d_ws, size_t ws_size,
                              hipStream_t stream) {
    const float* x   = (const float*)d_in[0];
    const float* A1  = (const float*)d_in[1];
    const float* B1  = (const float*)d_in[2];
    const float* A2  = (const float*)d_in[3];
    const float* B2  = (const float*)d_in[4];
    const float* b1  = (const float*)d_in[5];
    const float* b2  = (const float*)d_in[6];
    const int*   piv = (const int*)d_in[7];
    const int*   q   = (const int*)d_in[8];
    float* out = (float*)d_out;

    const int tokens = in_sizes[0] / DIN;          // 4096
    const int grid   = tokens / T_TOK;             // 512

    const size_t shmem = (size_t)LDS_FLOATS * sizeof(float);  // 149504 B
    // opt-in for >64KB dynamic LDS (idempotent, not stream-ordered)
    (void)hipFuncSetAttribute((const void*)kn_fused,
                              hipFuncAttributeMaxDynamicSharedMemorySize,
                              (int)shmem);

    kn_fused<<<grid, NTHREADS, shmem, stream>>>(x, A1, B1, A2, B2, b1, b2, piv, q, out);
}